// Round 3
// 438.636 us; speedup vs baseline: 1.0333x; 1.0333x over previous
//
#include <hip/hip_runtime.h>

typedef float f32x4 __attribute__((ext_vector_type(4)));

// Per-species standardization constants (H=idx0, O=idx1), padded to 9.
__constant__ float c_mus[2][9] = {
  {-0.0013891633279463555f, 0.052817133273316774f, 0.139812833597163f, 0.04197082575153015f,
   0.f, 0.f, 0.f, 0.f, 0.f},
  {0.3869724094534165f, 1.1195726605859562f, 4.597656411500856f, 4.18116756869605f,
   -0.777753667038269f, 0.8991094564592526f, 0.25287442792706855f, 0.f, 0.f}
};
__constant__ float c_sgs[2][9] = {
  {0.014984132924379046f, 0.06597323056314336f, 0.05229082868259066f, 0.10317217531939492f,
   1.f, 1.f, 1.f, 1.f, 1.f},
  {0.01648580936203453f, 0.04360467004470585f, 0.10939958699162289f, 0.1452881891452822f,
   0.24744978852384295f, 0.6757096584771374f, 0.15629951845443388f, 1.f, 1.f}
};
// triu_indices(12, k=1): 66 pairs
__constant__ unsigned char c_ii[66] = {
  0,0,0,0,0,0,0,0,0,0,0,
  1,1,1,1,1,1,1,1,1,1,
  2,2,2,2,2,2,2,2,2,
  3,3,3,3,3,3,3,3,
  4,4,4,4,4,4,4,
  5,5,5,5,5,5,
  6,6,6,6,6,
  7,7,7,7,
  8,8,8,
  9,9,
  10
};
__constant__ unsigned char c_jj[66] = {
  1,2,3,4,5,6,7,8,9,10,11,
  2,3,4,5,6,7,8,9,10,11,
  3,4,5,6,7,8,9,10,11,
  4,5,6,7,8,9,10,11,
  5,6,7,8,9,10,11,
  6,7,8,9,10,11,
  7,8,9,10,11,
  8,9,10,11,
  9,10,11,
  10,11,
  11
};
// cos/sin of OShfZ[z] = z*pi/7, z=0..7
__constant__ float c_cosZ[8] = {
  1.0f, 0.90096886790241915f, 0.62348980185873359f, 0.22252093395631439f,
  -0.22252093395631439f, -0.62348980185873359f, -0.90096886790241915f, -1.0f
};
__constant__ float c_sinZ[8] = {
  0.0f, 0.43388373911755823f, 0.78183148246802969f, 0.97492791218182362f,
  0.97492791218182362f, 0.78183148246802969f, 0.43388373911755823f, 0.0f
};

// One 256-thread block per atom. Output per atom: 4560 floats = 1140 float4.
__global__ __launch_bounds__(256)
void aev_kernel(const float* __restrict__ coeff, const int* __restrict__ species,
                float* __restrict__ out, int ntotal) {
  const int A = blockIdx.x;
  if (A >= ntotal) return;
  const int tid = threadIdx.x;

  __shared__ float sh_coef[45];
  __shared__ float sh_sn[9];
  __shared__ float sh_dist[12];
  __shared__ float sh_u[12][3];
  __shared__ __align__(16) float sh_f1[66 * 8];   // holds 2*f1 (factor folded)
  __shared__ __align__(16) float sh_f2[66 * 8];

  if (tid < 45) sh_coef[tid] = coeff[(size_t)A * 45 + tid];
  __syncthreads();

  const int sidx = (species[A] == 8) ? 1 : 0;

  if (tid < 9) {
    sh_sn[tid] = (sh_coef[tid] - c_mus[sidx][tid]) / c_sgs[sidx][tid];
  } else if (tid >= 16 && tid < 28) {
    int k = tid - 16;
    float x, y, z;
    if (k < 4) {                       // p vectors
      x = sh_coef[9 + 3 * k]; y = sh_coef[10 + 3 * k]; z = sh_coef[11 + 3 * k];
    } else if (k < 8) {                // reordered d, first half: orig (0,2,5)
      int b = 21 + 6 * (k - 4);
      x = sh_coef[b + 0]; y = sh_coef[b + 2]; z = sh_coef[b + 5];
    } else {                           // reordered d, second half: orig (4,3,1)
      int b = 21 + 6 * (k - 8);
      x = sh_coef[b + 4]; y = sh_coef[b + 3]; z = sh_coef[b + 1];
    }
    float d = sqrtf(x * x + y * y + z * z);
    bool zero = (fabsf(x) < 1e-12f) && (fabsf(y) < 1e-12f) && (fabsf(z) < 1e-12f);
    float inv = zero ? 0.f : 1.f / d;
    sh_dist[k] = d;
    sh_u[k][0] = x * inv; sh_u[k][1] = y * inv; sh_u[k][2] = z * inv;
  }
  __syncthreads();

  if (tid < 66) {
    int i = c_ii[tid], j = c_jj[tid];
    float cosang = sh_u[i][0] * sh_u[j][0] + sh_u[i][1] * sh_u[j][1] + sh_u[i][2] * sh_u[j][2];
    float c = 0.9999f * cosang;                 // cos(arccos(0.9999*cos)) == c
    float s = sqrtf(fmaxf(1.f - c * c, 0.f));   // sin(angle) >= 0 on [0,pi]
    float av = 0.5f * (sh_dist[i] + sh_dist[j]);
#pragma unroll
    for (int z = 0; z < 8; ++z) {
      float cz = c * c_cosZ[z] + s * c_sinZ[z]; // cos(angle - OShfZ[z])
      float b = (1.f + cz) * 0.5f;
      float b2 = b * b;
      float b4 = b2 * b2;
      sh_f1[tid * 8 + z] = 2.f * (b4 * b4);     // 2 * b^OZeta (=8), factor folded
      float da = av - (float)z * (2.f / 7.f);   // OShfA[z]
      sh_f2[tid * 8 + z] = __expf(-8.f * da * da);
    }
  }
  __syncthreads();

  f32x4* out4 = (f32x4*)out + (size_t)A * 1140;

  // ---- iteration 0: q = tid, mixed regions (s_aev | r_aev | ang) ----
  {
    const int q = tid;
    const int i = q * 4;
    f32x4 v;
    if (i < 144) {                      // s_aev: j*16 + t
      int j = i >> 4, t = i & 15;
      float sn = sh_sn[j];
#pragma unroll
      for (int m = 0; m < 4; ++m) {
        float d = sn - (-4.f + (float)(t + m) * (8.f / 15.f));
        v[m] = __expf(-4.f * d * d);
      }
    } else if (i < 336) {               // r_aev: k*16 + t
      int e = i - 144;
      int k = e >> 4, t = e & 15;
      float dd = sh_dist[k];
#pragma unroll
      for (int m = 0; m < 4; ++m) {
        float d = dd - (float)(t + m) * (2.f / 15.f);
        v[m] = __expf(-4.f * d * d);
      }
    } else {                            // ang: p*64 + z*8 + a
      int e = i - 336;
      int p = e >> 6, z = (e >> 3) & 7, a = e & 7;   // a in {0,4}
      float f1v = sh_f1[p * 8 + z];                  // already includes *2
      f32x4 f2v = *(const f32x4*)&sh_f2[p * 8 + a];
      v = f1v * f2v;
    }
    __builtin_nontemporal_store(v, &out4[q]);
  }

  // ---- iterations 1..4: pure ang region (q >= 256 ==> i >= 336) ----
  // q = tid + 256*it;  e = 4q-336 = 4*(q-84);  u = q-84
  // p = u>>4 (advances by +16 per it), z = (u>>1)&7 (invariant), a = (tid&1)*4 (invariant)
  // => LDS float index advances by exactly 128 per iteration (512 B);
  //    store index q advances by 256 float4 per iteration.
  {
    const int a  = (tid & 1) * 4;
    const int u0 = tid + 256 - 84;
    const int p0 = u0 >> 4;
    const int z0 = (u0 >> 1) & 7;
    const float* f1b = &sh_f1[p0 * 8 + z0];
    const float* f2b = &sh_f2[p0 * 8 + a];      // 16B-aligned (a in {0,4})
    f32x4* ob = out4 + (tid + 256);
#pragma unroll
    for (int it = 0; it < 3; ++it) {            // q = tid+256, +512, +768 (all < 1140)
      float f1v = f1b[it * 128];
      f32x4 f2v = *(const f32x4*)&f2b[it * 128];
      f32x4 v = f1v * f2v;
      __builtin_nontemporal_store(v, &ob[it * 256]);
    }
    if (tid < 116) {                            // q = tid + 1024 < 1140
      float f1v = f1b[3 * 128];
      f32x4 f2v = *(const f32x4*)&f2b[3 * 128];
      f32x4 v = f1v * f2v;
      __builtin_nontemporal_store(v, &ob[3 * 256]);
    }
  }
}

extern "C" void kernel_launch(void* const* d_in, const int* in_sizes, int n_in,
                              void* d_out, int out_size, void* d_ws, size_t ws_size,
                              hipStream_t stream) {
  const float* coeff = (const float*)d_in[0];
  const int* species = (const int*)d_in[1];
  float* out = (float*)d_out;
  int ntotal = in_sizes[1];  // nconf * natoms = 24576
  hipLaunchKernelGGL(aev_kernel, dim3(ntotal), dim3(256), 0, stream,
                     coeff, species, out, ntotal);
}